// Round 1
// baseline (616.560 us; speedup 1.0000x reference)
//
#include <hip/hip_runtime.h>
#include <hip/hip_bf16.h>

typedef unsigned short ushortT;
typedef unsigned int uintT;
typedef __attribute__((ext_vector_type(8))) short bf16x8;
typedef __attribute__((ext_vector_type(4))) float f32x4;

__device__ __forceinline__ ushortT f2bf(float f) {
    union { float f; uintT u; } x; x.f = f;
    uintT r = x.u + 0x7fffu + ((x.u >> 16) & 1u);
    return (ushortT)(r >> 16);
}
__device__ __forceinline__ float bf2f(ushortT u) {
    union { uintT u; float f; } x; x.u = ((uintT)u) << 16; return x.f;
}

// ---------------------------------------------------------------------------
// K0: column-softmax of W1/W2, e = emb @ sW, row-normalize.  grid=2 (e1, e2)
// ---------------------------------------------------------------------------
__global__ __launch_bounds__(256) void k_embed(const float* __restrict__ emb,
                                               const float* __restrict__ W1,
                                               const float* __restrict__ W2,
                                               float* __restrict__ e1,
                                               float* __restrict__ e2) {
    __shared__ float sW[800];
    __shared__ float sWs[800];
    const float* W = (blockIdx.x == 0) ? W1 : W2;
    float* e = (blockIdx.x == 0) ? e1 : e2;
    int tid = threadIdx.x;
    for (int i = tid; i < 800; i += 256) sW[i] = W[i];
    __syncthreads();
    if (tid < 20) {
        float mx = -1e30f;
        for (int i = 0; i < 40; ++i) mx = fmaxf(mx, sW[i * 20 + tid]);
        float s = 0.f;
        for (int i = 0; i < 40; ++i) s += __expf(sW[i * 20 + tid] - mx);
        float inv = 1.f / s;
        for (int i = 0; i < 40; ++i) sWs[i * 20 + tid] = __expf(sW[i * 20 + tid] - mx) * inv;
    }
    __syncthreads();
    for (int row = tid; row < 512; row += 256) {
        float acc[20];
        #pragma unroll
        for (int j = 0; j < 20; ++j) acc[j] = 0.f;
        for (int i = 0; i < 40; ++i) {
            float ev = emb[row * 40 + i];
            #pragma unroll
            for (int j = 0; j < 20; ++j) acc[j] += ev * sWs[i * 20 + j];
        }
        float s = 0.f;
        #pragma unroll
        for (int j = 0; j < 20; ++j) s += acc[j] * acc[j];
        float scale = 1.f / (sqrtf(s) + 1e-8f);
        #pragma unroll
        for (int j = 0; j < 20; ++j) e[row * 20 + j] = acc[j] * scale;
    }
}

// ---------------------------------------------------------------------------
// K1: A[v][w] = adj>0 ? e1[v].e2[w] + adj : 9e-15 ; d[v] = 1/sqrt(rowsum)
// grid = 512 (one block per row v)
// ---------------------------------------------------------------------------
__global__ __launch_bounds__(256) void k_adj(const float* __restrict__ adj,
                                             const float* __restrict__ e1,
                                             const float* __restrict__ e2,
                                             float* __restrict__ A,
                                             float* __restrict__ d) {
    int v = blockIdx.x, tid = threadIdx.x;
    __shared__ float ev[20];
    if (tid < 20) ev[tid] = e1[v * 20 + tid];
    __syncthreads();
    float local = 0.f;
    for (int w = tid; w < 512; w += 256) {
        float dot = 0.f;
        #pragma unroll
        for (int j = 0; j < 20; ++j) dot += ev[j] * e2[w * 20 + j];
        float av = adj[v * 512 + w];
        float Av = (av > 0.f) ? (dot + av) : 9e-15f;
        A[v * 512 + w] = Av;
        local += Av;
    }
    __shared__ float red[256];
    red[tid] = local;
    __syncthreads();
    for (int s = 128; s > 0; s >>= 1) {
        if (tid < s) red[tid] += red[tid + s];
        __syncthreads();
    }
    if (tid == 0) d[v] = 1.f / sqrtf(red[0]);
}

// ---------------------------------------------------------------------------
// K2: P slot1 = M[w][v] = Ls^T = -d[v]*d[w]*A[v][w] (bf16);  slot0 = I
// grid = 512 (block per output row w)
// ---------------------------------------------------------------------------
__global__ __launch_bounds__(256) void k_m(const float* __restrict__ A,
                                           const float* __restrict__ d,
                                           ushortT* __restrict__ P) {
    int w = blockIdx.x, tid = threadIdx.x;
    float dw = d[w];
    for (int v = tid; v < 512; v += 256) {
        float val = -d[v] * dw * A[v * 512 + w];
        P[512 * 512 + w * 512 + v] = f2bf(val);
        P[w * 512 + v] = (v == w) ? f2bf(1.f) : (ushortT)0;
    }
}

// ---------------------------------------------------------------------------
// K3: per-q MLP weights. q=0: sum of mlp_w blocks 0..3 ; q>=1: block q+3.
// Wq layout: [10][64 (o)][64 (c)] bf16
// ---------------------------------------------------------------------------
__global__ __launch_bounds__(256) void k_w(const float* __restrict__ mlp_w,
                                           ushortT* __restrict__ Wq) {
    int idx = blockIdx.x * 256 + threadIdx.x;
    if (idx >= 10 * 64 * 64) return;
    int q = idx >> 12, rem = idx & 4095, o = rem >> 6, c = rem & 63;
    float v;
    if (q == 0) {
        v = 0.f;
        #pragma unroll
        for (int k = 0; k < 4; ++k) v += mlp_w[o * 832 + k * 64 + c];
    } else {
        v = mlp_w[o * 832 + (q + 3) * 64 + c];
    }
    Wq[idx] = f2bf(v);
}

// ---------------------------------------------------------------------------
// 512x512x512 bf16 MFMA GEMM, epilogue builds Chebyshev combos.
// mode 0: out1 = bf16(C)
// mode 1: out1 = bf16(C), out2 = bf16(2C - I)
// mode 2: out1 = bf16(C), out2 = bf16(4C - 3*aux)
// grid = 64 blocks (8x8 of 64x64 tiles), block = 256 (4 waves, each 64x16)
// ---------------------------------------------------------------------------
__global__ __launch_bounds__(256) void k_gemm512(const ushortT* __restrict__ A,
                                                 const ushortT* __restrict__ B,
                                                 ushortT* __restrict__ out1,
                                                 ushortT* __restrict__ out2,
                                                 int mode,
                                                 const ushortT* __restrict__ aux) {
    int wave = threadIdx.x >> 6, lane = threadIdx.x & 63;
    int lr = lane & 15, lg = lane >> 4;
    int mbase = (blockIdx.x >> 3) * 64;
    int nbase = (blockIdx.x & 7) * 64 + wave * 16;
    f32x4 acc[4] = {};
    for (int kk = 0; kk < 16; ++kk) {
        int k0 = kk * 32 + lg * 8;
        bf16x8 bfr;
        #pragma unroll
        for (int j = 0; j < 8; ++j) bfr[j] = (short)B[(k0 + j) * 512 + nbase + lr];
        #pragma unroll
        for (int wt = 0; wt < 4; ++wt) {
            bf16x8 af = *(const bf16x8*)(A + (mbase + wt * 16 + lr) * 512 + k0);
            acc[wt] = __builtin_amdgcn_mfma_f32_16x16x32_bf16(af, bfr, acc[wt], 0, 0, 0);
        }
    }
    #pragma unroll
    for (int wt = 0; wt < 4; ++wt)
        #pragma unroll
        for (int r = 0; r < 4; ++r) {
            int row = mbase + wt * 16 + lg * 4 + r;
            int col = nbase + lr;
            float v = acc[wt][r];
            out1[row * 512 + col] = f2bf(v);
            if (mode == 1) out2[row * 512 + col] = f2bf(2.f * v - (row == col ? 1.f : 0.f));
            else if (mode == 2) out2[row * 512 + col] = f2bf(4.f * v - 3.f * bf2f(aux[row * 512 + col]));
        }
}

// ---------------------------------------------------------------------------
// Main fused kernel: workgroup = (b, t, node-half). 8 waves, 32 out-rows each.
// For q = 0..9:  Y = P_q[rows,:] @ X_bt   (MFMA, X from LDS, P from global/L2)
//                out_acc += Y @ Wq^T      (via per-wave LDS bounce of Y)
// Epilogue: out = relu(out_acc + x + bias)
// ---------------------------------------------------------------------------
__global__ __launch_bounds__(512, 1) void k_main(const float* __restrict__ x,
                                                 const ushortT* __restrict__ P,
                                                 const ushortT* __restrict__ Wq,
                                                 const float* __restrict__ bias,
                                                 float* __restrict__ out) {
    __shared__ ushortT Xlds[64 * 512];      // [c][v], v-groups XOR-swizzled
    __shared__ ushortT Yscr[8][32][72];     // per-wave private bounce buffer
    int bid = blockIdx.x;
    int b = bid / 24, rr = bid % 24, t = rr >> 1, half = rr & 1;
    int tid = threadIdx.x, wave = tid >> 6, lane = tid & 63;
    int lr = lane & 15, lg = lane >> 4;

    // ---- stage X_bt (512 nodes x 64 ch) into LDS, transposed + swizzled ----
    const float* xb = x + ((size_t)b * 6144 + t) * 64;  // xb[v*768 + c]
    {
        int c = lane;
        for (int it = 0; it < 32; ++it) {
            int v0 = it * 16 + wave * 2;
            float f0 = xb[(size_t)v0 * 768 + c];
            float f1 = xb[(size_t)(v0 + 1) * 768 + c];
            uintT u = (((uintT)f2bf(f1)) << 16) | (uintT)f2bf(f0);
            int gp = (v0 >> 3) ^ (c & 7);
            *(uintT*)&Xlds[c * 512 + gp * 8 + (v0 & 7)] = u;
        }
    }
    __syncthreads();

    int wbase = half * 256 + wave * 32;
    f32x4 oacc[2][4] = {};

    for (int q = 0; q < 10; ++q) {
        const ushortT* Pq = P + (size_t)q * (512 * 512);
        f32x4 acc[2][4] = {};
        for (int kk = 0; kk < 16; ++kk) {
            int v0 = kk * 32 + lg * 8;
            bf16x8 a0 = *(const bf16x8*)(Pq + (wbase + lr) * 512 + v0);
            bf16x8 a1 = *(const bf16x8*)(Pq + (wbase + 16 + lr) * 512 + v0);
            #pragma unroll
            for (int ct = 0; ct < 4; ++ct) {
                int cc = ct * 16 + lr;
                bf16x8 bfr = *(const bf16x8*)&Xlds[cc * 512 + (((v0 >> 3) ^ (cc & 7)) << 3)];
                acc[0][ct] = __builtin_amdgcn_mfma_f32_16x16x32_bf16(a0, bfr, acc[0][ct], 0, 0, 0);
                acc[1][ct] = __builtin_amdgcn_mfma_f32_16x16x32_bf16(a1, bfr, acc[1][ct], 0, 0, 0);
            }
        }
        // bounce Y (32x64) through per-wave LDS scratch: C/D layout -> A layout
        #pragma unroll
        for (int wt = 0; wt < 2; ++wt)
            #pragma unroll
            for (int ct = 0; ct < 4; ++ct)
                #pragma unroll
                for (int r = 0; r < 4; ++r)
                    Yscr[wave][wt * 16 + lg * 4 + r][ct * 16 + lr] = f2bf(acc[wt][ct][r]);
        // (same-wave DS ops are in-order; compiler inserts lgkmcnt waits)
        const ushortT* Wb = Wq + q * 4096;
        #pragma unroll
        for (int k2 = 0; k2 < 2; ++k2) {
            int c0 = k2 * 32 + lg * 8;
            bf16x8 y0 = *(const bf16x8*)&Yscr[wave][lr][c0];
            bf16x8 y1 = *(const bf16x8*)&Yscr[wave][16 + lr][c0];
            #pragma unroll
            for (int ot = 0; ot < 4; ++ot) {
                bf16x8 wf = *(const bf16x8*)(Wb + (ot * 16 + lr) * 64 + c0);
                oacc[0][ot] = __builtin_amdgcn_mfma_f32_16x16x32_bf16(y0, wf, oacc[0][ot], 0, 0, 0);
                oacc[1][ot] = __builtin_amdgcn_mfma_f32_16x16x32_bf16(y1, wf, oacc[1][ot], 0, 0, 0);
            }
        }
    }

    // ---- epilogue: residual + bias + relu, fp32 out ----
    #pragma unroll
    for (int wt = 0; wt < 2; ++wt)
        #pragma unroll
        for (int ot = 0; ot < 4; ++ot)
            #pragma unroll
            for (int r = 0; r < 4; ++r) {
                int w = wbase + wt * 16 + lg * 4 + r;
                int o = ot * 16 + lr;
                size_t oi = (((size_t)b * 512 + w) * 12 + t) * 64 + o;
                float v = oacc[wt][ot][r] + x[oi] + bias[o];
                out[oi] = (v > 0.f) ? v : 0.f;
            }
}

// ---------------------------------------------------------------------------
extern "C" void kernel_launch(void* const* d_in, const int* in_sizes, int n_in,
                              void* d_out, int out_size, void* d_ws, size_t ws_size,
                              hipStream_t stream) {
    const float* x    = (const float*)d_in[0];
    const float* adj  = (const float*)d_in[1];
    const float* emb  = (const float*)d_in[2];
    const float* W1   = (const float*)d_in[3];
    const float* W2   = (const float*)d_in[4];
    const float* mlpw = (const float*)d_in[5];
    const float* mlpb = (const float*)d_in[6];
    float* out = (float*)d_out;

    char* ws = (char*)d_ws;
    float*   e1   = (float*)(ws + 0);
    float*   e2   = (float*)(ws + 65536);
    float*   A    = (float*)(ws + 131072);
    float*   dvec = (float*)(ws + 131072 + 1048576);
    ushortT* P    = (ushortT*)(ws + 1183744);            // [10][512][512] bf16
    ushortT* Wq   = (ushortT*)(ws + 1183744 + 5242880);  // [10][64][64]  bf16

    k_embed<<<2, 256, 0, stream>>>(emb, W1, W2, e1, e2);
    k_adj<<<512, 256, 0, stream>>>(adj, e1, e2, A, dvec);
    k_m<<<512, 256, 0, stream>>>(A, dvec, P);
    k_w<<<160, 256, 0, stream>>>(mlpw, Wq);

    const int SZ = 512 * 512;
    ushortT *S1 = P + 1 * SZ, *S2 = P + 2 * SZ, *S3 = P + 3 * SZ, *S4 = P + 4 * SZ,
            *S5 = P + 5 * SZ, *S6 = P + 6 * SZ, *S7 = P + 7 * SZ, *S8 = P + 8 * SZ,
            *S9 = P + 9 * SZ;
    // S2 = M^2 ; S4 = 2M^2 - I (T2^T)
    k_gemm512<<<64, 256, 0, stream>>>(S1, S1, S2, S4, 1, nullptr);
    // S3 = M^3 ; S7 = 4M^3 - 3M (T3^T)
    k_gemm512<<<64, 256, 0, stream>>>(S1, S2, S3, S7, 2, S1);
    // S5 = (T2^T)^2 ; S6 = (T2^T)^3
    k_gemm512<<<64, 256, 0, stream>>>(S4, S4, S5, nullptr, 0, nullptr);
    k_gemm512<<<64, 256, 0, stream>>>(S4, S5, S6, nullptr, 0, nullptr);
    // S8 = (T3^T)^2 ; S9 = (T3^T)^3
    k_gemm512<<<64, 256, 0, stream>>>(S7, S7, S8, nullptr, 0, nullptr);
    k_gemm512<<<64, 256, 0, stream>>>(S7, S8, S9, nullptr, 0, nullptr);

    k_main<<<768, 512, 0, stream>>>(x, P, Wq, mlpb, out);
    (void)in_sizes; (void)n_in; (void)out_size; (void)ws_size;
}

// Round 2
// 520.767 us; speedup vs baseline: 1.1839x; 1.1839x over previous
//
#include <hip/hip_runtime.h>
#include <hip/hip_bf16.h>

typedef unsigned short ushortT;
typedef unsigned int uintT;
typedef __attribute__((ext_vector_type(8))) short bf16x8;
typedef __attribute__((ext_vector_type(4))) float f32x4;
typedef __attribute__((ext_vector_type(4))) unsigned short us4;

__device__ __forceinline__ ushortT f2bf(float f) {
    union { float f; uintT u; } x; x.f = f;
    uintT r = x.u + 0x7fffu + ((x.u >> 16) & 1u);
    return (ushortT)(r >> 16);
}
__device__ __forceinline__ float bf2f(ushortT u) {
    union { uintT u; float f; } x; x.u = ((uintT)u) << 16; return x.f;
}

// ---------------------------------------------------------------------------
// K0: column-softmax of W1/W2, e = emb @ sW, row-normalize.  grid=2 (e1, e2)
// ---------------------------------------------------------------------------
__global__ __launch_bounds__(256) void k_embed(const float* __restrict__ emb,
                                               const float* __restrict__ W1,
                                               const float* __restrict__ W2,
                                               float* __restrict__ e1,
                                               float* __restrict__ e2) {
    __shared__ float sW[800];
    __shared__ float sWs[800];
    const float* W = (blockIdx.x == 0) ? W1 : W2;
    float* e = (blockIdx.x == 0) ? e1 : e2;
    int tid = threadIdx.x;
    for (int i = tid; i < 800; i += 256) sW[i] = W[i];
    __syncthreads();
    if (tid < 20) {
        float mx = -1e30f;
        for (int i = 0; i < 40; ++i) mx = fmaxf(mx, sW[i * 20 + tid]);
        float s = 0.f;
        for (int i = 0; i < 40; ++i) s += __expf(sW[i * 20 + tid] - mx);
        float inv = 1.f / s;
        for (int i = 0; i < 40; ++i) sWs[i * 20 + tid] = __expf(sW[i * 20 + tid] - mx) * inv;
    }
    __syncthreads();
    for (int row = tid; row < 512; row += 256) {
        float acc[20];
        #pragma unroll
        for (int j = 0; j < 20; ++j) acc[j] = 0.f;
        for (int i = 0; i < 40; ++i) {
            float ev = emb[row * 40 + i];
            #pragma unroll
            for (int j = 0; j < 20; ++j) acc[j] += ev * sWs[i * 20 + j];
        }
        float s = 0.f;
        #pragma unroll
        for (int j = 0; j < 20; ++j) s += acc[j] * acc[j];
        float scale = 1.f / (sqrtf(s) + 1e-8f);
        #pragma unroll
        for (int j = 0; j < 20; ++j) e[row * 20 + j] = acc[j] * scale;
    }
}

// ---------------------------------------------------------------------------
// K1: A[v][w] = adj>0 ? e1[v].e2[w] + adj : 9e-15 ; d[v] = 1/sqrt(rowsum)
// ---------------------------------------------------------------------------
__global__ __launch_bounds__(256) void k_adj(const float* __restrict__ adj,
                                             const float* __restrict__ e1,
                                             const float* __restrict__ e2,
                                             float* __restrict__ A,
                                             float* __restrict__ d) {
    int v = blockIdx.x, tid = threadIdx.x;
    __shared__ float ev[20];
    if (tid < 20) ev[tid] = e1[v * 20 + tid];
    __syncthreads();
    float local = 0.f;
    for (int w = tid; w < 512; w += 256) {
        float dot = 0.f;
        #pragma unroll
        for (int j = 0; j < 20; ++j) dot += ev[j] * e2[w * 20 + j];
        float av = adj[v * 512 + w];
        float Av = (av > 0.f) ? (dot + av) : 9e-15f;
        A[v * 512 + w] = Av;
        local += Av;
    }
    __shared__ float red[256];
    red[tid] = local;
    __syncthreads();
    for (int s = 128; s > 0; s >>= 1) {
        if (tid < s) red[tid] += red[tid + s];
        __syncthreads();
    }
    if (tid == 0) d[v] = 1.f / sqrtf(red[0]);
}

// ---------------------------------------------------------------------------
// K2: P slot1 = M[w][v] = Ls^T = -d[v]*d[w]*A[v][w] (bf16). slot0 unused now.
// ---------------------------------------------------------------------------
__global__ __launch_bounds__(256) void k_m(const float* __restrict__ A,
                                           const float* __restrict__ d,
                                           ushortT* __restrict__ P) {
    int w = blockIdx.x, tid = threadIdx.x;
    float dw = d[w];
    for (int v = tid; v < 512; v += 256) {
        float val = -d[v] * dw * A[v * 512 + w];
        P[512 * 512 + w * 512 + v] = f2bf(val);
    }
}

// ---------------------------------------------------------------------------
// K3: per-q MLP weights. q=0: sum of mlp_w blocks 0..3 ; q>=1: block q+3.
// ---------------------------------------------------------------------------
__global__ __launch_bounds__(256) void k_w(const float* __restrict__ mlp_w,
                                           ushortT* __restrict__ Wq) {
    int idx = blockIdx.x * 256 + threadIdx.x;
    if (idx >= 10 * 64 * 64) return;
    int q = idx >> 12, rem = idx & 4095, o = rem >> 6, c = rem & 63;
    float v;
    if (q == 0) {
        v = 0.f;
        #pragma unroll
        for (int k = 0; k < 4; ++k) v += mlp_w[o * 832 + k * 64 + c];
    } else {
        v = mlp_w[o * 832 + (q + 3) * 64 + c];
    }
    Wq[idx] = f2bf(v);
}

// ---------------------------------------------------------------------------
// 512x512x512 bf16 MFMA GEMM (+Chebyshev epilogue). Supports a second
// independent GEMM in blocks 64..127 (A2/B2/out3, mode 0).
// ---------------------------------------------------------------------------
__global__ __launch_bounds__(256) void k_gemm512(const ushortT* __restrict__ A,
                                                 const ushortT* __restrict__ B,
                                                 ushortT* __restrict__ out1,
                                                 ushortT* __restrict__ out2,
                                                 int mode,
                                                 const ushortT* __restrict__ aux,
                                                 const ushortT* __restrict__ A2,
                                                 const ushortT* __restrict__ B2,
                                                 ushortT* __restrict__ out3) {
    int bx = blockIdx.x;
    if (bx >= 64) { A = A2; B = B2; out1 = out3; out2 = nullptr; mode = 0; bx -= 64; }
    int wave = threadIdx.x >> 6, lane = threadIdx.x & 63;
    int lr = lane & 15, lg = lane >> 4;
    int mbase = (bx >> 3) * 64;
    int nbase = (bx & 7) * 64 + wave * 16;
    f32x4 acc[4] = {};
    for (int kk = 0; kk < 16; ++kk) {
        int k0 = kk * 32 + lg * 8;
        bf16x8 bfr;
        #pragma unroll
        for (int j = 0; j < 8; ++j) bfr[j] = (short)B[(k0 + j) * 512 + nbase + lr];
        #pragma unroll
        for (int wt = 0; wt < 4; ++wt) {
            bf16x8 af = *(const bf16x8*)(A + (mbase + wt * 16 + lr) * 512 + k0);
            acc[wt] = __builtin_amdgcn_mfma_f32_16x16x32_bf16(af, bfr, acc[wt], 0, 0, 0);
        }
    }
    #pragma unroll
    for (int wt = 0; wt < 4; ++wt)
        #pragma unroll
        for (int r = 0; r < 4; ++r) {
            int row = mbase + wt * 16 + lg * 4 + r;
            int col = nbase + lr;
            float v = acc[wt][r];
            out1[row * 512 + col] = f2bf(v);
            if (mode == 1) out2[row * 512 + col] = f2bf(2.f * v - (row == col ? 1.f : 0.f));
            else if (mode == 2) out2[row * 512 + col] = f2bf(4.f * v - 3.f * bf2f(aux[row * 512 + col]));
        }
}

// ---------------------------------------------------------------------------
// Main fused kernel v2:  out = relu(x + bias + sum_q P_q @ (X @ Wq^T))
//   Z_q = X @ Wq^T computed per q into one 64KB LDS buffer (Z^T, swizzled);
//   big GEMM accumulates directly into oacc; X lives in registers.
//   768 blocks (b,t,half) x 512 threads; 2 blocks/CU, 4 waves/SIMD.
// ---------------------------------------------------------------------------
__global__ __launch_bounds__(512, 4) void k_main(const float* __restrict__ x,
                                                 const ushortT* __restrict__ P,
                                                 const ushortT* __restrict__ Wq,
                                                 const float* __restrict__ bias,
                                                 float* __restrict__ out) {
    __shared__ ushortT Zt[64 * 512];   // Z^T[o][v], v XOR-swizzled by ((o&7)<<3)
    const int SZ = 512 * 512;
    int bid = blockIdx.x;
    int b = bid / 24, rr = bid % 24, t = rr >> 1, half = rr & 1;
    int tid = threadIdx.x, wave = tid >> 6, lane = tid & 63;
    int lr = lane & 15, lg = lane >> 4;
    int wbase = half * 256 + wave * 32;   // wave's 32 output rows
    int vbase = wave * 64;                // wave's 64 Z-compute rows
    int mk = (lr & 7) << 3;               // v-swizzle mask (o&7 == lr&7)

    // ---- X rows for this wave's Z-compute, held in registers as bf16 ----
    bf16x8 xa[4][2];
    #pragma unroll
    for (int vt = 0; vt < 4; ++vt)
        #pragma unroll
        for (int k2 = 0; k2 < 2; ++k2) {
            const float* px = x + (((size_t)b * 512 + vbase + vt * 16 + lr) * 12 + t) * 64
                              + k2 * 32 + lg * 8;
            f32x4 f0 = *(const f32x4*)px;
            f32x4 f1 = *(const f32x4*)(px + 4);
            bf16x8 v;
            v[0] = (short)f2bf(f0[0]); v[1] = (short)f2bf(f0[1]);
            v[2] = (short)f2bf(f0[2]); v[3] = (short)f2bf(f0[3]);
            v[4] = (short)f2bf(f1[0]); v[5] = (short)f2bf(f1[1]);
            v[6] = (short)f2bf(f1[2]); v[7] = (short)f2bf(f1[3]);
            xa[vt][k2] = v;
        }

    // ---- Z-phase: Zt = (X @ Wq^T)^T for one q ----
    auto zphase = [&](int q) {
        const ushortT* wqp = Wq + q * 4096;
        #pragma unroll
        for (int ot = 0; ot < 4; ++ot) {
            int o = ot * 16 + lr;
            bf16x8 wf0 = *(const bf16x8*)(wqp + o * 64 + lg * 8);
            bf16x8 wf1 = *(const bf16x8*)(wqp + o * 64 + 32 + lg * 8);
            f32x4 z0 = {}, z1 = {}, z2 = {}, z3 = {};
            z0 = __builtin_amdgcn_mfma_f32_16x16x32_bf16(xa[0][0], wf0, z0, 0, 0, 0);
            z0 = __builtin_amdgcn_mfma_f32_16x16x32_bf16(xa[0][1], wf1, z0, 0, 0, 0);
            z1 = __builtin_amdgcn_mfma_f32_16x16x32_bf16(xa[1][0], wf0, z1, 0, 0, 0);
            z1 = __builtin_amdgcn_mfma_f32_16x16x32_bf16(xa[1][1], wf1, z1, 0, 0, 0);
            z2 = __builtin_amdgcn_mfma_f32_16x16x32_bf16(xa[2][0], wf0, z2, 0, 0, 0);
            z2 = __builtin_amdgcn_mfma_f32_16x16x32_bf16(xa[2][1], wf1, z2, 0, 0, 0);
            z3 = __builtin_amdgcn_mfma_f32_16x16x32_bf16(xa[3][0], wf0, z3, 0, 0, 0);
            z3 = __builtin_amdgcn_mfma_f32_16x16x32_bf16(xa[3][1], wf1, z3, 0, 0, 0);
            int zb = o * 512;
            {
                int v0 = vbase + 0 * 16 + lg * 4;
                us4 pk = { f2bf(z0[0]), f2bf(z0[1]), f2bf(z0[2]), f2bf(z0[3]) };
                *(us4*)&Zt[zb + (v0 ^ mk)] = pk;
            }
            {
                int v0 = vbase + 1 * 16 + lg * 4;
                us4 pk = { f2bf(z1[0]), f2bf(z1[1]), f2bf(z1[2]), f2bf(z1[3]) };
                *(us4*)&Zt[zb + (v0 ^ mk)] = pk;
            }
            {
                int v0 = vbase + 2 * 16 + lg * 4;
                us4 pk = { f2bf(z2[0]), f2bf(z2[1]), f2bf(z2[2]), f2bf(z2[3]) };
                *(us4*)&Zt[zb + (v0 ^ mk)] = pk;
            }
            {
                int v0 = vbase + 3 * 16 + lg * 4;
                us4 pk = { f2bf(z3[0]), f2bf(z3[1]), f2bf(z3[2]), f2bf(z3[3]) };
                *(us4*)&Zt[zb + (v0 ^ mk)] = pk;
            }
        }
    };

    f32x4 oacc[2][4] = {};
    bf16x8 a0r[4], a1r[4];

    // ---- q = 0: identity support -> oacc = Z_0 directly ----
    zphase(0);
    __syncthreads();
    #pragma unroll
    for (int wt = 0; wt < 2; ++wt)
        #pragma unroll
        for (int ot = 0; ot < 4; ++ot) {
            int o = ot * 16 + lr;
            int w0 = wbase + wt * 16 + lg * 4;
            us4 z4 = *(const us4*)&Zt[o * 512 + (w0 ^ mk)];
            oacc[wt][ot][0] = bf2f(z4[0]);
            oacc[wt][ot][1] = bf2f(z4[1]);
            oacc[wt][ot][2] = bf2f(z4[2]);
            oacc[wt][ot][3] = bf2f(z4[3]);
        }
    // preload P-fragment ring for q=1, kk=0..3
    {
        const ushortT* pq0 = P + (size_t)SZ + (size_t)(wbase + lr) * 512 + lg * 8;
        #pragma unroll
        for (int s = 0; s < 4; ++s) {
            a0r[s] = *(const bf16x8*)(pq0 + s * 32);
            a1r[s] = *(const bf16x8*)(pq0 + 8192 + s * 32);
        }
    }
    __syncthreads();

    // ---- q = 1..9: Z-phase then big GEMM with depth-4 prefetch ring ----
    for (int q = 1; q <= 9; ++q) {
        zphase(q);
        __syncthreads();
        const ushortT* pq  = P + (size_t)q * SZ + (size_t)(wbase + lr) * 512 + lg * 8;
        const ushortT* pqn = pq + SZ;
        #pragma unroll
        for (int kk = 0; kk < 16; ++kk) {
            const int slot = kk & 3;
            int vb = (kk * 32 + lg * 8) ^ mk;
            bf16x8 b0 = *(const bf16x8*)&Zt[(0 * 16 + lr) * 512 + vb];
            bf16x8 b1 = *(const bf16x8*)&Zt[(1 * 16 + lr) * 512 + vb];
            bf16x8 b2 = *(const bf16x8*)&Zt[(2 * 16 + lr) * 512 + vb];
            bf16x8 b3 = *(const bf16x8*)&Zt[(3 * 16 + lr) * 512 + vb];
            oacc[0][0] = __builtin_amdgcn_mfma_f32_16x16x32_bf16(a0r[slot], b0, oacc[0][0], 0, 0, 0);
            oacc[1][0] = __builtin_amdgcn_mfma_f32_16x16x32_bf16(a1r[slot], b0, oacc[1][0], 0, 0, 0);
            oacc[0][1] = __builtin_amdgcn_mfma_f32_16x16x32_bf16(a0r[slot], b1, oacc[0][1], 0, 0, 0);
            oacc[1][1] = __builtin_amdgcn_mfma_f32_16x16x32_bf16(a1r[slot], b1, oacc[1][1], 0, 0, 0);
            oacc[0][2] = __builtin_amdgcn_mfma_f32_16x16x32_bf16(a0r[slot], b2, oacc[0][2], 0, 0, 0);
            oacc[1][2] = __builtin_amdgcn_mfma_f32_16x16x32_bf16(a1r[slot], b2, oacc[1][2], 0, 0, 0);
            oacc[0][3] = __builtin_amdgcn_mfma_f32_16x16x32_bf16(a0r[slot], b3, oacc[0][3], 0, 0, 0);
            oacc[1][3] = __builtin_amdgcn_mfma_f32_16x16x32_bf16(a1r[slot], b3, oacc[1][3], 0, 0, 0);
            if (kk < 12) {
                a0r[slot] = *(const bf16x8*)(pq + (kk + 4) * 32);
                a1r[slot] = *(const bf16x8*)(pq + 8192 + (kk + 4) * 32);
            } else if (q < 9) {
                a0r[slot] = *(const bf16x8*)(pqn + (kk - 12) * 32);
                a1r[slot] = *(const bf16x8*)(pqn + 8192 + (kk - 12) * 32);
            }
        }
        __syncthreads();
    }

    // ---- epilogue: residual + bias + relu, fp32 out ----
    #pragma unroll
    for (int wt = 0; wt < 2; ++wt)
        #pragma unroll
        for (int ot = 0; ot < 4; ++ot)
            #pragma unroll
            for (int r = 0; r < 4; ++r) {
                int w = wbase + wt * 16 + lg * 4 + r;
                int o = ot * 16 + lr;
                size_t oi = (((size_t)b * 512 + w) * 12 + t) * 64 + o;
                float v = oacc[wt][ot][r] + x[oi] + bias[o];
                out[oi] = (v > 0.f) ? v : 0.f;
            }
}

// ---------------------------------------------------------------------------
extern "C" void kernel_launch(void* const* d_in, const int* in_sizes, int n_in,
                              void* d_out, int out_size, void* d_ws, size_t ws_size,
                              hipStream_t stream) {
    const float* x    = (const float*)d_in[0];
    const float* adj  = (const float*)d_in[1];
    const float* emb  = (const float*)d_in[2];
    const float* W1   = (const float*)d_in[3];
    const float* W2   = (const float*)d_in[4];
    const float* mlpw = (const float*)d_in[5];
    const float* mlpb = (const float*)d_in[6];
    float* out = (float*)d_out;

    char* ws = (char*)d_ws;
    float*   e1   = (float*)(ws + 0);
    float*   e2   = (float*)(ws + 65536);
    float*   A    = (float*)(ws + 131072);
    float*   dvec = (float*)(ws + 131072 + 1048576);
    ushortT* P    = (ushortT*)(ws + 1183744);            // [10][512][512] bf16 (slot0 unused)
    ushortT* Wq   = (ushortT*)(ws + 1183744 + 5242880);  // [10][64][64]  bf16

    k_embed<<<2, 256, 0, stream>>>(emb, W1, W2, e1, e2);
    k_adj<<<512, 256, 0, stream>>>(adj, e1, e2, A, dvec);
    k_m<<<512, 256, 0, stream>>>(A, dvec, P);
    k_w<<<160, 256, 0, stream>>>(mlpw, Wq);

    const int SZ = 512 * 512;
    ushortT *S1 = P + 1 * SZ, *S2 = P + 2 * SZ, *S3 = P + 3 * SZ, *S4 = P + 4 * SZ,
            *S5 = P + 5 * SZ, *S6 = P + 6 * SZ, *S7 = P + 7 * SZ, *S8 = P + 8 * SZ,
            *S9 = P + 9 * SZ;
    // S2 = M^2 ; S4 = 2M^2 - I (T2^T)
    k_gemm512<<<64, 256, 0, stream>>>(S1, S1, S2, S4, 1, nullptr, nullptr, nullptr, nullptr);
    // S3 = M^3 ; S7 = 4M^3 - 3M (T3^T)
    k_gemm512<<<64, 256, 0, stream>>>(S1, S2, S3, S7, 2, S1, nullptr, nullptr, nullptr);
    // S5 = (T2^T)^2  ||  S8 = (T3^T)^2
    k_gemm512<<<128, 256, 0, stream>>>(S4, S4, S5, nullptr, 0, nullptr, S7, S7, S8);
    // S6 = (T2^T)^3  ||  S9 = (T3^T)^3
    k_gemm512<<<128, 256, 0, stream>>>(S4, S5, S6, nullptr, 0, nullptr, S7, S8, S9);

    k_main<<<768, 512, 0, stream>>>(x, P, Wq, mlpb, out);
    (void)in_sizes; (void)n_in; (void)out_size; (void)ws_size;
}

// Round 3
// 374.931 us; speedup vs baseline: 1.6445x; 1.3890x over previous
//
#include <hip/hip_runtime.h>
#include <hip/hip_bf16.h>

typedef unsigned short ushortT;
typedef unsigned int uintT;
typedef __attribute__((ext_vector_type(8))) short bf16x8;
typedef __attribute__((ext_vector_type(4))) float f32x4;
typedef __attribute__((ext_vector_type(4))) unsigned short us4;

__device__ __forceinline__ ushortT f2bf(float f) {
    union { float f; uintT u; } x; x.f = f;
    uintT r = x.u + 0x7fffu + ((x.u >> 16) & 1u);
    return (ushortT)(r >> 16);
}
__device__ __forceinline__ float bf2f(ushortT u) {
    union { uintT u; float f; } x; x.u = ((uintT)u) << 16; return x.f;
}

// ---------------------------------------------------------------------------
// K0: column-softmax of W1/W2, e = emb @ sW, row-normalize.  grid=2 (e1, e2)
// ---------------------------------------------------------------------------
__global__ __launch_bounds__(256) void k_embed(const float* __restrict__ emb,
                                               const float* __restrict__ W1,
                                               const float* __restrict__ W2,
                                               float* __restrict__ e1,
                                               float* __restrict__ e2) {
    __shared__ float sW[800];
    __shared__ float sWs[800];
    const float* W = (blockIdx.x == 0) ? W1 : W2;
    float* e = (blockIdx.x == 0) ? e1 : e2;
    int tid = threadIdx.x;
    for (int i = tid; i < 800; i += 256) sW[i] = W[i];
    __syncthreads();
    if (tid < 20) {
        float mx = -1e30f;
        for (int i = 0; i < 40; ++i) mx = fmaxf(mx, sW[i * 20 + tid]);
        float s = 0.f;
        for (int i = 0; i < 40; ++i) s += __expf(sW[i * 20 + tid] - mx);
        float inv = 1.f / s;
        for (int i = 0; i < 40; ++i) sWs[i * 20 + tid] = __expf(sW[i * 20 + tid] - mx) * inv;
    }
    __syncthreads();
    for (int row = tid; row < 512; row += 256) {
        float acc[20];
        #pragma unroll
        for (int j = 0; j < 20; ++j) acc[j] = 0.f;
        for (int i = 0; i < 40; ++i) {
            float ev = emb[row * 40 + i];
            #pragma unroll
            for (int j = 0; j < 20; ++j) acc[j] += ev * sWs[i * 20 + j];
        }
        float s = 0.f;
        #pragma unroll
        for (int j = 0; j < 20; ++j) s += acc[j] * acc[j];
        float scale = 1.f / (sqrtf(s) + 1e-8f);
        #pragma unroll
        for (int j = 0; j < 20; ++j) e[row * 20 + j] = acc[j] * scale;
    }
}

// ---------------------------------------------------------------------------
// K1: A[v][w] = adj>0 ? e1[v].e2[w] + adj : 9e-15 ; d[v] = 1/sqrt(rowsum)
// ---------------------------------------------------------------------------
__global__ __launch_bounds__(256) void k_adj(const float* __restrict__ adj,
                                             const float* __restrict__ e1,
                                             const float* __restrict__ e2,
                                             float* __restrict__ A,
                                             float* __restrict__ d) {
    int v = blockIdx.x, tid = threadIdx.x;
    __shared__ float ev[20];
    if (tid < 20) ev[tid] = e1[v * 20 + tid];
    __syncthreads();
    float local = 0.f;
    for (int w = tid; w < 512; w += 256) {
        float dot = 0.f;
        #pragma unroll
        for (int j = 0; j < 20; ++j) dot += ev[j] * e2[w * 20 + j];
        float av = adj[v * 512 + w];
        float Av = (av > 0.f) ? (dot + av) : 9e-15f;
        A[v * 512 + w] = Av;
        local += Av;
    }
    __shared__ float red[256];
    red[tid] = local;
    __syncthreads();
    for (int s = 128; s > 0; s >>= 1) {
        if (tid < s) red[tid] += red[tid + s];
        __syncthreads();
    }
    if (tid == 0) d[v] = 1.f / sqrtf(red[0]);
}

// ---------------------------------------------------------------------------
// K2: P slot1 = M[w][v] = Ls^T = -d[v]*d[w]*A[v][w] (bf16)
// ---------------------------------------------------------------------------
__global__ __launch_bounds__(256) void k_m(const float* __restrict__ A,
                                           const float* __restrict__ d,
                                           ushortT* __restrict__ P) {
    int w = blockIdx.x, tid = threadIdx.x;
    float dw = d[w];
    for (int v = tid; v < 512; v += 256) {
        float val = -d[v] * dw * A[v * 512 + w];
        P[512 * 512 + w * 512 + v] = f2bf(val);
    }
}

// ---------------------------------------------------------------------------
// K3: per-q MLP weights. q=0: sum of mlp_w blocks 0..3 ; q>=1: block q+3.
// ---------------------------------------------------------------------------
__global__ __launch_bounds__(256) void k_w(const float* __restrict__ mlp_w,
                                           ushortT* __restrict__ Wq) {
    int idx = blockIdx.x * 256 + threadIdx.x;
    if (idx >= 10 * 64 * 64) return;
    int q = idx >> 12, rem = idx & 4095, o = rem >> 6, c = rem & 63;
    float v;
    if (q == 0) {
        v = 0.f;
        #pragma unroll
        for (int k = 0; k < 4; ++k) v += mlp_w[o * 832 + k * 64 + c];
    } else {
        v = mlp_w[o * 832 + (q + 3) * 64 + c];
    }
    Wq[idx] = f2bf(v);
}

// ---------------------------------------------------------------------------
// K4: x (f32, [b][v][t][c]) -> xbf (bf16, [b][t][v][c]).  grid = 12288 x 256.
// ---------------------------------------------------------------------------
__global__ __launch_bounds__(256) void k_xbf(const float* __restrict__ x,
                                             ushortT* __restrict__ xbf) {
    size_t i = (size_t)blockIdx.x * 256 + threadIdx.x;
    int c = (int)(i & 15) * 4;
    int v = (int)((i >> 4) & 511);
    int bt = (int)(i >> 13);            // b*12 + t
    int b = bt / 12, t = bt - b * 12;
    f32x4 f = *(const f32x4*)(x + (((size_t)b * 512 + v) * 12 + t) * 64 + c);
    us4 o = { f2bf(f[0]), f2bf(f[1]), f2bf(f[2]), f2bf(f[3]) };
    *(us4*)(xbf + ((size_t)bt * 512 + v) * 64 + c) = o;
}

// ---------------------------------------------------------------------------
// 512x512x512 bf16 MFMA GEMM (+Chebyshev epilogue). Supports a second
// independent GEMM in blocks 64..127 (A2/B2/out3, mode 0).
// ---------------------------------------------------------------------------
__global__ __launch_bounds__(256) void k_gemm512(const ushortT* __restrict__ A,
                                                 const ushortT* __restrict__ B,
                                                 ushortT* __restrict__ out1,
                                                 ushortT* __restrict__ out2,
                                                 int mode,
                                                 const ushortT* __restrict__ aux,
                                                 const ushortT* __restrict__ A2,
                                                 const ushortT* __restrict__ B2,
                                                 ushortT* __restrict__ out3) {
    int bx = blockIdx.x;
    if (bx >= 64) { A = A2; B = B2; out1 = out3; out2 = nullptr; mode = 0; bx -= 64; }
    int wave = threadIdx.x >> 6, lane = threadIdx.x & 63;
    int lr = lane & 15, lg = lane >> 4;
    int mbase = (bx >> 3) * 64;
    int nbase = (bx & 7) * 64 + wave * 16;
    f32x4 acc[4] = {};
    for (int kk = 0; kk < 16; ++kk) {
        int k0 = kk * 32 + lg * 8;
        bf16x8 bfr;
        #pragma unroll
        for (int j = 0; j < 8; ++j) bfr[j] = (short)B[(k0 + j) * 512 + nbase + lr];
        #pragma unroll
        for (int wt = 0; wt < 4; ++wt) {
            bf16x8 af = *(const bf16x8*)(A + (mbase + wt * 16 + lr) * 512 + k0);
            acc[wt] = __builtin_amdgcn_mfma_f32_16x16x32_bf16(af, bfr, acc[wt], 0, 0, 0);
        }
    }
    #pragma unroll
    for (int wt = 0; wt < 4; ++wt)
        #pragma unroll
        for (int r = 0; r < 4; ++r) {
            int row = mbase + wt * 16 + lg * 4 + r;
            int col = nbase + lr;
            float v = acc[wt][r];
            out1[row * 512 + col] = f2bf(v);
            if (mode == 1) out2[row * 512 + col] = f2bf(2.f * v - (row == col ? 1.f : 0.f));
            else if (mode == 2) out2[row * 512 + col] = f2bf(4.f * v - 3.f * bf2f(aux[row * 512 + col]));
        }
}

// ---------------------------------------------------------------------------
// Main fused kernel v3:  out = relu(x + bias + sum_q P_q @ (X @ Wq^T))
//   Register-budget redesign: X fragments loaded from global per zphase
//   (bf16 via xbf when available, else f32+convert), prefetch ring depth 2.
//   Target: <=128 VGPR (no scratch spill) at 2 blocks/CU, 4 waves/SIMD.
// ---------------------------------------------------------------------------
template<bool XBF>
__global__ __launch_bounds__(512, 4) void k_main(const float* __restrict__ x,
                                                 const ushortT* __restrict__ xbf,
                                                 const ushortT* __restrict__ P,
                                                 const ushortT* __restrict__ Wq,
                                                 const float* __restrict__ bias,
                                                 float* __restrict__ out) {
    __shared__ ushortT Zt[64 * 512];   // Z^T[o][v], v XOR-swizzled by ((o&7)<<3)
    const int SZ = 512 * 512;
    int bid = blockIdx.x;
    int b = bid / 24, rr = bid % 24, tt = rr >> 1, half = rr & 1;
    int tid = threadIdx.x, wave = tid >> 6, lane = tid & 63;
    int lr = lane & 15, lg = lane >> 4;
    int wbase = half * 256 + wave * 32;   // wave's 32 output rows
    int vbase = wave * 64;                // wave's 64 Z-compute rows
    int mk = (lr & 7) << 3;               // v-swizzle mask

    const ushortT* xq = xbf + ((size_t)(b * 12 + tt) * 512 + vbase) * 64;
    const float*   xqf = x + ((size_t)(b * 512 + vbase) * 12 + tt) * 64;

    f32x4 oacc[2][4] = {};
    bf16x8 a0r[2], a1r[2];
    // preload ring (q=1, kk=0..1) — no barrier dependency, issue immediately
    {
        const ushortT* pq1 = P + (size_t)SZ + (size_t)(wbase + lr) * 512 + lg * 8;
        a0r[0] = *(const bf16x8*)(pq1);
        a0r[1] = *(const bf16x8*)(pq1 + 32);
        a1r[0] = *(const bf16x8*)(pq1 + 8192);
        a1r[1] = *(const bf16x8*)(pq1 + 8192 + 32);
    }

    for (int q = 0; q <= 9; ++q) {
        // ---- zphase: Zt = (X @ Wq^T)^T ----
        bf16x8 xf[8];
        #pragma unroll
        for (int vt = 0; vt < 4; ++vt) {
            if (XBF) {
                xf[vt * 2 + 0] = *(const bf16x8*)(xq + (vt * 16 + lr) * 64 + lg * 8);
                xf[vt * 2 + 1] = *(const bf16x8*)(xq + (vt * 16 + lr) * 64 + 32 + lg * 8);
            } else {
                const float* px = xqf + (size_t)(vt * 16 + lr) * 768 + lg * 8;
                f32x4 f0 = *(const f32x4*)px;
                f32x4 f1 = *(const f32x4*)(px + 4);
                f32x4 f2 = *(const f32x4*)(px + 32);
                f32x4 f3 = *(const f32x4*)(px + 36);
                bf16x8 v0, v1;
                v0[0] = (short)f2bf(f0[0]); v0[1] = (short)f2bf(f0[1]);
                v0[2] = (short)f2bf(f0[2]); v0[3] = (short)f2bf(f0[3]);
                v0[4] = (short)f2bf(f1[0]); v0[5] = (short)f2bf(f1[1]);
                v0[6] = (short)f2bf(f1[2]); v0[7] = (short)f2bf(f1[3]);
                v1[0] = (short)f2bf(f2[0]); v1[1] = (short)f2bf(f2[1]);
                v1[2] = (short)f2bf(f2[2]); v1[3] = (short)f2bf(f2[3]);
                v1[4] = (short)f2bf(f3[0]); v1[5] = (short)f2bf(f3[1]);
                v1[6] = (short)f2bf(f3[2]); v1[7] = (short)f2bf(f3[3]);
                xf[vt * 2 + 0] = v0;
                xf[vt * 2 + 1] = v1;
            }
        }
        const ushortT* wqp = Wq + q * 4096;
        #pragma unroll
        for (int ot = 0; ot < 4; ++ot) {
            int o = ot * 16 + lr;
            bf16x8 wf0 = *(const bf16x8*)(wqp + o * 64 + lg * 8);
            bf16x8 wf1 = *(const bf16x8*)(wqp + o * 64 + 32 + lg * 8);
            f32x4 z0 = {}, z1 = {}, z2 = {}, z3 = {};
            z0 = __builtin_amdgcn_mfma_f32_16x16x32_bf16(xf[0], wf0, z0, 0, 0, 0);
            z0 = __builtin_amdgcn_mfma_f32_16x16x32_bf16(xf[1], wf1, z0, 0, 0, 0);
            z1 = __builtin_amdgcn_mfma_f32_16x16x32_bf16(xf[2], wf0, z1, 0, 0, 0);
            z1 = __builtin_amdgcn_mfma_f32_16x16x32_bf16(xf[3], wf1, z1, 0, 0, 0);
            z2 = __builtin_amdgcn_mfma_f32_16x16x32_bf16(xf[4], wf0, z2, 0, 0, 0);
            z2 = __builtin_amdgcn_mfma_f32_16x16x32_bf16(xf[5], wf1, z2, 0, 0, 0);
            z3 = __builtin_amdgcn_mfma_f32_16x16x32_bf16(xf[6], wf0, z3, 0, 0, 0);
            z3 = __builtin_amdgcn_mfma_f32_16x16x32_bf16(xf[7], wf1, z3, 0, 0, 0);
            int zb = o * 512;
            {
                int v0i = vbase + 0 * 16 + lg * 4;
                us4 pk = { f2bf(z0[0]), f2bf(z0[1]), f2bf(z0[2]), f2bf(z0[3]) };
                *(us4*)&Zt[zb + (v0i ^ mk)] = pk;
            }
            {
                int v0i = vbase + 1 * 16 + lg * 4;
                us4 pk = { f2bf(z1[0]), f2bf(z1[1]), f2bf(z1[2]), f2bf(z1[3]) };
                *(us4*)&Zt[zb + (v0i ^ mk)] = pk;
            }
            {
                int v0i = vbase + 2 * 16 + lg * 4;
                us4 pk = { f2bf(z2[0]), f2bf(z2[1]), f2bf(z2[2]), f2bf(z2[3]) };
                *(us4*)&Zt[zb + (v0i ^ mk)] = pk;
            }
            {
                int v0i = vbase + 3 * 16 + lg * 4;
                us4 pk = { f2bf(z3[0]), f2bf(z3[1]), f2bf(z3[2]), f2bf(z3[3]) };
                *(us4*)&Zt[zb + (v0i ^ mk)] = pk;
            }
        }
        __syncthreads();

        if (q == 0) {
            // identity support: oacc = Z_0 directly
            #pragma unroll
            for (int wt = 0; wt < 2; ++wt)
                #pragma unroll
                for (int ot = 0; ot < 4; ++ot) {
                    int o = ot * 16 + lr;
                    int w0 = wbase + wt * 16 + lg * 4;
                    us4 z4 = *(const us4*)&Zt[o * 512 + (w0 ^ mk)];
                    oacc[wt][ot][0] = bf2f(z4[0]);
                    oacc[wt][ot][1] = bf2f(z4[1]);
                    oacc[wt][ot][2] = bf2f(z4[2]);
                    oacc[wt][ot][3] = bf2f(z4[3]);
                }
        } else {
            const ushortT* pq  = P + (size_t)q * SZ + (size_t)(wbase + lr) * 512 + lg * 8;
            const ushortT* pqn = pq + SZ;
            #pragma unroll
            for (int kk = 0; kk < 16; ++kk) {
                const int slot = kk & 1;
                int vb = (kk * 32 + lg * 8) ^ mk;
                bf16x8 b0 = *(const bf16x8*)&Zt[(0 * 16 + lr) * 512 + vb];
                bf16x8 b1 = *(const bf16x8*)&Zt[(1 * 16 + lr) * 512 + vb];
                bf16x8 b2 = *(const bf16x8*)&Zt[(2 * 16 + lr) * 512 + vb];
                bf16x8 b3 = *(const bf16x8*)&Zt[(3 * 16 + lr) * 512 + vb];
                oacc[0][0] = __builtin_amdgcn_mfma_f32_16x16x32_bf16(a0r[slot], b0, oacc[0][0], 0, 0, 0);
                oacc[1][0] = __builtin_amdgcn_mfma_f32_16x16x32_bf16(a1r[slot], b0, oacc[1][0], 0, 0, 0);
                oacc[0][1] = __builtin_amdgcn_mfma_f32_16x16x32_bf16(a0r[slot], b1, oacc[0][1], 0, 0, 0);
                oacc[1][1] = __builtin_amdgcn_mfma_f32_16x16x32_bf16(a1r[slot], b1, oacc[1][1], 0, 0, 0);
                oacc[0][2] = __builtin_amdgcn_mfma_f32_16x16x32_bf16(a0r[slot], b2, oacc[0][2], 0, 0, 0);
                oacc[1][2] = __builtin_amdgcn_mfma_f32_16x16x32_bf16(a1r[slot], b2, oacc[1][2], 0, 0, 0);
                oacc[0][3] = __builtin_amdgcn_mfma_f32_16x16x32_bf16(a0r[slot], b3, oacc[0][3], 0, 0, 0);
                oacc[1][3] = __builtin_amdgcn_mfma_f32_16x16x32_bf16(a1r[slot], b3, oacc[1][3], 0, 0, 0);
                if (kk < 14) {
                    a0r[slot] = *(const bf16x8*)(pq + (kk + 2) * 32);
                    a1r[slot] = *(const bf16x8*)(pq + 8192 + (kk + 2) * 32);
                } else if (q < 9) {
                    a0r[slot] = *(const bf16x8*)(pqn + (kk - 14) * 32);
                    a1r[slot] = *(const bf16x8*)(pqn + 8192 + (kk - 14) * 32);
                }
            }
        }
        __syncthreads();
    }

    // ---- epilogue: residual + bias + relu, fp32 out ----
    #pragma unroll
    for (int wt = 0; wt < 2; ++wt)
        #pragma unroll
        for (int ot = 0; ot < 4; ++ot)
            #pragma unroll
            for (int r = 0; r < 4; ++r) {
                int w = wbase + wt * 16 + lg * 4 + r;
                int o = ot * 16 + lr;
                size_t oi = (((size_t)b * 512 + w) * 12 + tt) * 64 + o;
                float v = oacc[wt][ot][r] + x[oi] + bias[o];
                out[oi] = (v > 0.f) ? v : 0.f;
            }
}

// ---------------------------------------------------------------------------
extern "C" void kernel_launch(void* const* d_in, const int* in_sizes, int n_in,
                              void* d_out, int out_size, void* d_ws, size_t ws_size,
                              hipStream_t stream) {
    const float* x    = (const float*)d_in[0];
    const float* adj  = (const float*)d_in[1];
    const float* emb  = (const float*)d_in[2];
    const float* W1   = (const float*)d_in[3];
    const float* W2   = (const float*)d_in[4];
    const float* mlpw = (const float*)d_in[5];
    const float* mlpb = (const float*)d_in[6];
    float* out = (float*)d_out;

    char* ws = (char*)d_ws;
    float*   e1   = (float*)(ws + 0);
    float*   e2   = (float*)(ws + 65536);
    float*   A    = (float*)(ws + 131072);
    float*   dvec = (float*)(ws + 1179648);
    ushortT* P    = (ushortT*)(ws + 1183744);            // [10][512][512] bf16 (slot0 unused)
    ushortT* Wq   = (ushortT*)(ws + 6426624);            // [10][64][64]  bf16
    ushortT* xbf  = (ushortT*)(ws + 6508544);            // [b][t][512][64] bf16 = 24MB
    const size_t WS_NEED = 6508544 + (size_t)32 * 12 * 512 * 64 * 2;
    const bool use_xbf = (ws_size >= WS_NEED);

    k_embed<<<2, 256, 0, stream>>>(emb, W1, W2, e1, e2);
    k_adj<<<512, 256, 0, stream>>>(adj, e1, e2, A, dvec);
    k_m<<<512, 256, 0, stream>>>(A, dvec, P);
    k_w<<<160, 256, 0, stream>>>(mlpw, Wq);
    if (use_xbf) k_xbf<<<12288, 256, 0, stream>>>(x, xbf);

    const int SZ = 512 * 512;
    ushortT *S1 = P + 1 * SZ, *S2 = P + 2 * SZ, *S3 = P + 3 * SZ, *S4 = P + 4 * SZ,
            *S5 = P + 5 * SZ, *S6 = P + 6 * SZ, *S7 = P + 7 * SZ, *S8 = P + 8 * SZ,
            *S9 = P + 9 * SZ;
    // S2 = M^2 ; S4 = 2M^2 - I (T2^T)
    k_gemm512<<<64, 256, 0, stream>>>(S1, S1, S2, S4, 1, nullptr, nullptr, nullptr, nullptr);
    // S3 = M^3 ; S7 = 4M^3 - 3M (T3^T)
    k_gemm512<<<64, 256, 0, stream>>>(S1, S2, S3, S7, 2, S1, nullptr, nullptr, nullptr);
    // S5 = (T2^T)^2  ||  S8 = (T3^T)^2
    k_gemm512<<<128, 256, 0, stream>>>(S4, S4, S5, nullptr, 0, nullptr, S7, S7, S8);
    // S6 = (T2^T)^3  ||  S9 = (T3^T)^3
    k_gemm512<<<128, 256, 0, stream>>>(S4, S5, S6, nullptr, 0, nullptr, S7, S8, S9);

    if (use_xbf)
        k_main<true><<<768, 512, 0, stream>>>(x, xbf, P, Wq, mlpb, out);
    else
        k_main<false><<<768, 512, 0, stream>>>(x, nullptr, P, Wq, mlpb, out);
    (void)in_sizes; (void)n_in; (void)out_size;
}